// Round 1
// baseline (430.736 us; speedup 1.0000x reference)
//
#include <hip/hip_runtime.h>

// SSIM, fused separable depthwise-conv version.
// img1, img2: [32, 3, 512, 512] fp32. Output: scalar mean of ssim_map (fp32).
//
// Kernel 1 (ssim_kernel): one block per 32x32 output tile per channel.
//   - stage x,y tile + 5-px halo (42x42) in LDS (stride 43: conflict-free)
//   - horizontal 11-tap Gaussian conv -> 5 LDS arrays [42][32] (stride 33)
//   - vertical 11-tap conv + SSIM formula per pixel, block-reduce,
//     write one float partial per block into d_ws.
// Kernel 2 (reduce_kernel): single block sums partials in double, writes mean.

#define WSZ   11
#define RAD   5
#define TILE  32
#define HALO  (TILE + 2 * RAD)   // 42
#define ISTR  43                 // input tile LDS row stride (odd)
#define HSTR  33                 // h-conv LDS row stride (odd)

#define C1 (0.01f * 0.01f)
#define C2 (0.03f * 0.03f)

__global__ __launch_bounds__(256) void ssim_kernel(
    const float* __restrict__ img1, const float* __restrict__ img2,
    float* __restrict__ partial, int H, int W, int tiles_x, int tiles_y)
{
    __shared__ float s1[HALO * ISTR];
    __shared__ float s2[HALO * ISTR];
    __shared__ float hx [HALO * HSTR];
    __shared__ float hy [HALO * HSTR];
    __shared__ float hxx[HALO * HSTR];
    __shared__ float hyy[HALO * HSTR];
    __shared__ float hxy[HALO * HSTR];
    __shared__ float wave_sums[4];

    const int tid = threadIdx.x;

    // Gaussian weights, computed in fp32 exactly like the reference
    // (exp(-(d^2)/(2*1.5^2)) then normalize).
    float w[WSZ];
    {
        float s = 0.f;
        #pragma unroll
        for (int i = 0; i < WSZ; ++i) {
            float d = (float)(i - RAD);
            w[i] = expf(-(d * d) / 4.5f);
            s += w[i];
        }
        #pragma unroll
        for (int i = 0; i < WSZ; ++i) w[i] /= s;
    }

    const int tiles_per_ch = tiles_x * tiles_y;
    const int ch = blockIdx.x / tiles_per_ch;
    const int t  = blockIdx.x - ch * tiles_per_ch;
    const int ty = t / tiles_x;
    const int tx = t - ty * tiles_x;
    const int row0 = ty * TILE - RAD;   // global row of LDS row 0
    const int col0 = tx * TILE - RAD;   // global col of LDS col 0

    const float* __restrict__ p1 = img1 + (size_t)ch * H * W;
    const float* __restrict__ p2 = img2 + (size_t)ch * H * W;

    // ---- stage inputs (zero-pad outside the image, matches SAME conv) ----
    for (int i = tid; i < HALO * HALO; i += 256) {
        int r = i / HALO;
        int c = i - r * HALO;
        int gr = row0 + r, gc = col0 + c;
        float v1 = 0.f, v2 = 0.f;
        if (gr >= 0 && gr < H && gc >= 0 && gc < W) {
            size_t off = (size_t)gr * W + gc;
            v1 = p1[off];
            v2 = p2[off];
        }
        s1[r * ISTR + c] = v1;
        s2[r * ISTR + c] = v2;
    }
    __syncthreads();

    // ---- horizontal conv: 42 rows x 32 cols, 5 quantities ----
    for (int i = tid; i < HALO * TILE; i += 256) {
        int r = i >> 5;        // 0..41
        int c = i & 31;        // 0..31
        const float* a = &s1[r * ISTR + c];
        const float* b = &s2[r * ISTR + c];
        float sx = 0.f, sy = 0.f, sxx = 0.f, syy = 0.f, sxy = 0.f;
        #pragma unroll
        for (int k = 0; k < WSZ; ++k) {
            float wk = w[k];
            float xv = a[k];
            float yv = b[k];
            sx  += wk * xv;
            sy  += wk * yv;
            sxx += wk * xv * xv;
            syy += wk * yv * yv;
            sxy += wk * xv * yv;
        }
        int o = r * HSTR + c;
        hx [o] = sx;
        hy [o] = sy;
        hxx[o] = sxx;
        hyy[o] = syy;
        hxy[o] = sxy;
    }
    __syncthreads();

    // ---- vertical conv + SSIM formula; 4 output rows per thread ----
    float acc = 0.f;
    const int c     = tid & 31;
    const int rbase = tid >> 5;          // 0..7
    #pragma unroll
    for (int j = 0; j < 4; ++j) {
        int r = rbase + 8 * j;           // 0..31
        float mu1 = 0.f, mu2 = 0.f, m11 = 0.f, m22 = 0.f, m12 = 0.f;
        #pragma unroll
        for (int k = 0; k < WSZ; ++k) {
            float wk = w[k];
            int o = (r + k) * HSTR + c;
            mu1 += wk * hx [o];
            mu2 += wk * hy [o];
            m11 += wk * hxx[o];
            m22 += wk * hyy[o];
            m12 += wk * hxy[o];
        }
        float mu1s = mu1 * mu1;
        float mu2s = mu2 * mu2;
        float mu12 = mu1 * mu2;
        float sig1 = m11 - mu1s;
        float sig2 = m22 - mu2s;
        float sig12 = m12 - mu12;
        float num = (2.f * mu12 + C1) * (2.f * sig12 + C2);
        float den = (mu1s + mu2s + C1) * (sig1 + sig2 + C2);
        acc += num / den;
    }

    // ---- block reduction: wave shuffle then LDS across 4 waves ----
    #pragma unroll
    for (int off = 32; off > 0; off >>= 1)
        acc += __shfl_down(acc, off);
    if ((tid & 63) == 0) wave_sums[tid >> 6] = acc;
    __syncthreads();
    if (tid == 0) {
        float bs = wave_sums[0] + wave_sums[1] + wave_sums[2] + wave_sums[3];
        partial[blockIdx.x] = bs;
    }
}

__global__ __launch_bounds__(256) void reduce_kernel(
    const float* __restrict__ partial, int n, float* __restrict__ out,
    double inv_count)
{
    __shared__ double wave_sums[4];
    const int tid = threadIdx.x;
    double s = 0.0;
    for (int i = tid; i < n; i += 256) s += (double)partial[i];
    #pragma unroll
    for (int off = 32; off > 0; off >>= 1)
        s += __shfl_down(s, off);
    if ((tid & 63) == 0) wave_sums[tid >> 6] = s;
    __syncthreads();
    if (tid == 0) {
        double bs = wave_sums[0] + wave_sums[1] + wave_sums[2] + wave_sums[3];
        out[0] = (float)(bs * inv_count);
    }
}

extern "C" void kernel_launch(void* const* d_in, const int* in_sizes, int n_in,
                              void* d_out, int out_size, void* d_ws, size_t ws_size,
                              hipStream_t stream)
{
    const float* img1 = (const float*)d_in[0];
    const float* img2 = (const float*)d_in[1];
    float* out = (float*)d_out;
    float* partial = (float*)d_ws;   // needs nblocks*4 = ~96 KB of scratch

    const int H = 512, W = 512;
    const int NC = 32 * 3;                 // N*C depthwise channels
    const int tiles_x = W / TILE;          // 16
    const int tiles_y = H / TILE;          // 16
    const int nblocks = NC * tiles_x * tiles_y;   // 24576

    ssim_kernel<<<nblocks, 256, 0, stream>>>(img1, img2, partial,
                                             H, W, tiles_x, tiles_y);

    const double inv_count = 1.0 / ((double)NC * H * W);
    reduce_kernel<<<1, 256, 0, stream>>>(partial, nblocks, out, inv_count);
}